// Round 13
// baseline (297.608 us; speedup 1.0000x reference)
//
#include <hip/hip_runtime.h>

// Problem constants
#define EMB  4096
#define DH   128      // QKV_DIM
#define NH   32       // N_HEADS
#define NTOK 16384    // B*S
#define NCOL 384      // qs | k | v columns

#define BM 32         // tokens per block; 4 waves, wave tile 32x96 (acc 2x6)

typedef __attribute__((ext_vector_type(8))) short short8;
typedef __attribute__((ext_vector_type(4))) float f32x4;

// f32 pair -> packed bf16x2, RNE (hardware cvt)
static __device__ __forceinline__ unsigned int cvt2(float a, float b) {
    unsigned int r;
    asm volatile("v_cvt_pk_bf16_f32 %0, %1, %2" : "=v"(r) : "v"(a), "v"(b));
    return r;
}
// pack 8 f32 -> 8 bf16 (K-order preserved)
static __device__ __forceinline__ short8 cvt8(const float4& x, const float4& y) {
    union { short8 v; unsigned int u[4]; } r;
    r.u[0] = cvt2(x.x, x.y);
    r.u[1] = cvt2(x.z, x.w);
    r.u[2] = cvt2(y.x, y.y);
    r.u[3] = cvt2(y.z, y.w);
    return r.v;
}
// scalar f32 -> bf16 bits, RNE (prep_w only)
static __device__ __forceinline__ unsigned short f2bf(float f) {
    unsigned int u = __builtin_bit_cast(unsigned int, f);
    u += 0x7fffu + ((u >> 16) & 1u);
    return (unsigned short)(u >> 16);
}
// single-instruction hardware exp2
static __device__ __forceinline__ float exp2_hw(float x) {
#if __has_builtin(__builtin_amdgcn_exp2f)
    return __builtin_amdgcn_exp2f(x);
#else
    float r;
    asm volatile("v_exp_f32 %0, %1\n\ts_nop 1" : "=v"(r) : "v"(x));
    return r;
#endif
}

// ---------------------------------------------------------------------------
// Kernel 1: build W3F — combined weights W3[384][4096] (bf16) in MFMA
// FRAGMENT-LINEAR order (proven R10-R12): panel p (=n>>6), k-tile kt (=D>>6),
// chunk (kh*4+jfr), lane: 16 B at
//   byte = p*524288 + kt*8192 + (kh*4+jfr)*1024 + lane*16
// hold B[n=jfr*16+lmod][D=kt*64+kh*32+lgrp*8+e] — one lane's B-fragment.
// Also bias[384].
// ---------------------------------------------------------------------------
__global__ void prep_w(const float* __restrict__ Wq, const float* __restrict__ bq,
                       const float* __restrict__ Wk, const float* __restrict__ bk,
                       const float* __restrict__ Wv, const float* __restrict__ bv,
                       unsigned short* __restrict__ W3F, float* __restrict__ bias) {
    const int tid = blockIdx.x * 256 + threadIdx.x;   // [0, 384*512)
    const int n  = tid >> 9;          // output column [0,384)
    const int ck = tid & 511;         // 8-element chunk of the 4096 K dim
    const int D0 = ck * 8;

    float v[8];
    if (n < DH) {
#pragma unroll
        for (int e = 0; e < 8; ++e) {
            const float4* p = (const float4*)(Wq + (size_t)(D0 + e) * (DH * NH) + n * NH);
            float s = 0.f;
#pragma unroll
            for (int i = 0; i < 8; ++i) { float4 q = p[i]; s += (q.x + q.y) + (q.z + q.w); }
            v[e] = s;
        }
    } else if (n < 2 * DH) {
#pragma unroll
        for (int e = 0; e < 8; ++e) v[e] = Wk[(size_t)(D0 + e) * DH + (n - DH)];
    } else {
#pragma unroll
        for (int e = 0; e < 8; ++e) v[e] = Wv[(size_t)(D0 + e) * DH + (n - 2 * DH)];
    }

    union { short8 s; unsigned int u[4]; } pk;
#pragma unroll
    for (int j = 0; j < 4; ++j)
        pk.u[j] = (unsigned int)f2bf(v[2 * j]) | ((unsigned int)f2bf(v[2 * j + 1]) << 16);

    const int p    = n >> 6, r = n & 63;
    const int jfr  = r >> 4, lmod = r & 15;
    const int kt   = ck >> 3;
    const int kh   = (ck >> 2) & 1;
    const int lgrp = ck & 3;
    const int lane = lgrp * 16 + lmod;
    char* dst = (char*)W3F + (size_t)p * 524288 + (size_t)kt * 8192
              + (kh * 4 + jfr) * 1024 + lane * 16;
    *(short8*)dst = pk.s;

    if (ck == 0) {
        float b;
        if (n < DH) {
            float s = 0.f;
#pragma unroll
            for (int h = 0; h < NH; ++h) s += bq[n * NH + h];
            b = s;
        } else if (n < 2 * DH) {
            b = bk[n - DH];
        } else {
            b = bv[n - 2 * DH];
        }
        bias[n] = b;
    }
}

// ---------------------------------------------------------------------------
// Kernel 2 (FUSED, barrier-free gemm): per 32-token stripe, each of 4 waves
// independently computes its 96 output cols over full K — A-fragments loaded
// DIRECTLY from X (8 consecutive f32/lane, no LDS, no barriers), B-fragments
// from fragment-linear W3F (L2-resident). All loads consumed in-iteration, so
// waves/blocks desync freely and memory stalls interleave (pure TLP).
// Then ONE barrier, rank-1 softmax with hw exp2, shfl-broadcast out-write.
// qsm layout per token (f32): [0..128) = q; [128+2e]=k_e, [129+2e]=v_e.
// ---------------------------------------------------------------------------
__global__ __launch_bounds__(256, 2) void fused_mqa(const float* __restrict__ X,
                         const unsigned short* __restrict__ W3F,
                         const float* __restrict__ bias,
                         float* __restrict__ out) {
    __shared__ float qsm[BM * NCOL];                        // 48 KB

    // XCD-bijective remap over 512 blocks (64 per XCD)
    const int bid  = blockIdx.x;
    const int wkid = (bid & 7) * 64 + (bid >> 3);
    const int m0   = wkid * BM;

    const int t = threadIdx.x, lane = t & 63, w = t >> 6;   // w in {0..3}
    const int lmod = lane & 15, lgrp = lane >> 4;

    f32x4 acc[2][6] = {};

    // A-fragment rows (direct from X): row i*16+lmod, k = kb + kh*32 + lgrp*8
    const float* xr0 = X + (size_t)(m0 + lmod) * EMB + lgrp * 8;
    const float* xr1 = xr0 + (size_t)16 * EMB;

    // B-fragment base pointers: global frag col f = w*6+j
    const char* bp[6];
#pragma unroll
    for (int j = 0; j < 6; ++j) {
        const int f = w * 6 + j;
        bp[j] = (const char*)W3F + (size_t)(f >> 2) * 524288 + (f & 3) * 1024 + lane * 16;
    }

    for (int tt = 0; tt < EMB / 64; ++tt) {
        const int kb = tt * 64;
#pragma unroll
        for (int kh = 0; kh < 2; ++kh) {
            const int ko = kb + kh * 32;
            float4 a00 = *(const float4*)(xr0 + ko);
            float4 a01 = *(const float4*)(xr0 + ko + 4);
            float4 a10 = *(const float4*)(xr1 + ko);
            float4 a11 = *(const float4*)(xr1 + ko + 4);
            short8 bf[6];
#pragma unroll
            for (int j = 0; j < 6; ++j)
                bf[j] = *(const short8*)(bp[j] + (size_t)tt * 8192 + kh * 4096);
            const short8 af0 = cvt8(a00, a01);
            const short8 af1 = cvt8(a10, a11);
#pragma unroll
            for (int j = 0; j < 6; ++j) {
                acc[0][j] = __builtin_amdgcn_mfma_f32_16x16x32_bf16(af0, bf[j], acc[0][j], 0, 0, 0);
                acc[1][j] = __builtin_amdgcn_mfma_f32_16x16x32_bf16(af1, bf[j], acc[1][j], 0, 0, 0);
            }
        }
    }

    // ---- epilogue 1: acc + bias -> qsm (q linear, k/v interleaved) ----
    // C/D layout: col = lane&15, row(token) = (lane>>4)*4 + reg
#pragma unroll
    for (int j = 0; j < 6; ++j) {
        const int col = w * 96 + j * 16 + lmod;
        const float bj = bias[col];
        const int slot = (col < 128) ? col : ((col < 256) ? 2 * col - 128 : 2 * col - 383);
#pragma unroll
        for (int i = 0; i < 2; ++i) {
            const int tokr = i * 16 + (lgrp << 2);
#pragma unroll
            for (int r = 0; r < 4; ++r)
                qsm[(tokr + r) * NCOL + slot] = acc[i][j][r] + bj;
        }
    }
    __syncthreads();

    // ---- epilogue 2: per-token rank-1 softmax (hw exp2) + shfl broadcast ----
    const float c = 0.088388347648318447f * 1.4426950408889634f; // scale*log2(e)
    for (int tok = w; tok < BM; tok += 4) {
        const float* row = &qsm[tok * NCOL];
        const float a0 = row[lane] * c;
        const float a1 = row[64 + lane] * c;
        const float kk0 = row[128 + 2 * lane];
        const float kk1 = row[256 + 2 * lane];

        float lmax = fmaxf(kk0, kk1), lmin = fminf(kk0, kk1);
#pragma unroll
        for (int off = 32; off; off >>= 1) {
            lmax = fmaxf(lmax, __shfl_xor(lmax, off));
            lmin = fminf(lmin, __shfl_xor(lmin, off));
        }
        const float m0v = (a0 >= 0.f) ? a0 * lmax : a0 * lmin;
        const float m1v = (a1 >= 0.f) ? a1 * lmax : a1 * lmin;

        float s00 = 0.f, s01 = 0.f, s10 = 0.f, s11 = 0.f;
#pragma unroll 8
        for (int e = 0; e < DH; ++e) {
            const float2 kv = *(const float2*)&row[128 + 2 * e];   // broadcast
            const float p0 = exp2_hw(fmaf(a0, kv.x, -m0v));
            const float p1 = exp2_hw(fmaf(a1, kv.x, -m1v));
            s00 += p0;  s01 = fmaf(p0, kv.y, s01);
            s10 += p1;  s11 = fmaf(p1, kv.y, s11);
        }
        const float o0 = s01 / s00;           // o[d], d = lane
        const float o1 = s11 / s10;           // o[d], d = 64 + lane

        float* orow = out + (size_t)(m0 + tok) * (DH * NH);
#pragma unroll
        for (int it = 0; it < 16; ++it) {
            const int idx = it * 64 + lane;              // float4 index in row
            const int src = (it & 7) * 8 + (lane >> 3);  // d & 63
            const float val = (it < 8) ? __shfl(o0, src) : __shfl(o1, src);
            float4 f4; f4.x = val; f4.y = val; f4.z = val; f4.w = val;
            *(float4*)(orow + idx * 4) = f4;
        }
    }
}

// ---------------------------------------------------------------------------
extern "C" void kernel_launch(void* const* d_in, const int* in_sizes, int n_in,
                              void* d_out, int out_size, void* d_ws, size_t ws_size,
                              hipStream_t stream) {
    const float* x  = (const float*)d_in[0];
    const float* Wq = (const float*)d_in[1];
    const float* bq = (const float*)d_in[2];
    const float* Wk = (const float*)d_in[3];
    const float* bk = (const float*)d_in[4];
    const float* Wv = (const float*)d_in[5];
    const float* bv = (const float*)d_in[6];
    float* out = (float*)d_out;

    char* ws = (char*)d_ws;
    unsigned short* W3F = (unsigned short*)ws;       // 6*524288 = 3,145,728 B
    float* bias = (float*)(ws + 3145728);            // 1,536 B

    prep_w<<<(NCOL * 512) / 256, 256, 0, stream>>>(Wq, bq, Wk, bk, Wv, bv, W3F, bias);
    fused_mqa<<<NTOK / BM, 256, 0, stream>>>(x, W3F, bias, out);
}

// Round 14
// 179.931 us; speedup vs baseline: 1.6540x; 1.6540x over previous
//
#include <hip/hip_runtime.h>

// Problem constants
#define EMB  4096
#define DH   128      // QKV_DIM
#define NH   32       // N_HEADS
#define NTOK 16384    // B*S
#define NCOL 384      // qs | k | v columns

// GEMM tile: 64(M) x 384(N=all) block, BK=64, 6 waves, wave tile 64x64 (acc 4x4)
#define BM 64
#define BK 64

typedef __attribute__((ext_vector_type(8))) short short8;
typedef __attribute__((ext_vector_type(4))) short short4_t;
typedef __attribute__((ext_vector_type(4))) float f32x4;

// f32 pair -> packed bf16x2, RNE (hardware cvt)
static __device__ __forceinline__ unsigned int cvt2(float a, float b) {
    unsigned int r;
    asm volatile("v_cvt_pk_bf16_f32 %0, %1, %2" : "=v"(r) : "v"(a), "v"(b));
    return r;
}
// scalar f32 -> bf16 bits, RNE (prep_w only)
static __device__ __forceinline__ unsigned short f2bf(float f) {
    unsigned int u = __builtin_bit_cast(unsigned int, f);
    u += 0x7fffu + ((u >> 16) & 1u);
    return (unsigned short)(u >> 16);
}
// single-instruction hardware exp2 (validated R13: absmax unchanged)
static __device__ __forceinline__ float exp2_hw(float x) {
#if __has_builtin(__builtin_amdgcn_exp2f)
    return __builtin_amdgcn_exp2f(x);
#else
    float r;
    asm volatile("v_exp_f32 %0, %1\n\ts_nop 1" : "=v"(r) : "v"(x));
    return r;
#endif
}

// ---------------------------------------------------------------------------
// Kernel 1: build W3F — combined weights W3[384][4096] (bf16) in MFMA
// FRAGMENT-LINEAR order (proven R10): panel p (=n>>6), k-tile kt (=D>>6),
// chunk (kh*4+jfr), lane: the 16 B at
//   byte = p*524288 + kt*8192 + (kh*4+jfr)*1024 + lane*16
// hold B[n=jfr*16+lmod][D=kt*64+kh*32+lgrp*8+e] — one lane's B-fragment.
// Also bias[384].
// ---------------------------------------------------------------------------
__global__ void prep_w(const float* __restrict__ Wq, const float* __restrict__ bq,
                       const float* __restrict__ Wk, const float* __restrict__ bk,
                       const float* __restrict__ Wv, const float* __restrict__ bv,
                       unsigned short* __restrict__ W3F, float* __restrict__ bias) {
    const int tid = blockIdx.x * 256 + threadIdx.x;   // [0, 384*512)
    const int n  = tid >> 9;          // output column [0,384)
    const int ck = tid & 511;         // 8-element chunk of the 4096 K dim
    const int D0 = ck * 8;

    float v[8];
    if (n < DH) {
#pragma unroll
        for (int e = 0; e < 8; ++e) {
            const float4* p = (const float4*)(Wq + (size_t)(D0 + e) * (DH * NH) + n * NH);
            float s = 0.f;
#pragma unroll
            for (int i = 0; i < 8; ++i) { float4 q = p[i]; s += (q.x + q.y) + (q.z + q.w); }
            v[e] = s;
        }
    } else if (n < 2 * DH) {
#pragma unroll
        for (int e = 0; e < 8; ++e) v[e] = Wk[(size_t)(D0 + e) * DH + (n - DH)];
    } else {
#pragma unroll
        for (int e = 0; e < 8; ++e) v[e] = Wv[(size_t)(D0 + e) * DH + (n - 2 * DH)];
    }

    union { short8 s; unsigned int u[4]; } pk;
#pragma unroll
    for (int j = 0; j < 4; ++j)
        pk.u[j] = (unsigned int)f2bf(v[2 * j]) | ((unsigned int)f2bf(v[2 * j + 1]) << 16);

    const int p    = n >> 6, r = n & 63;
    const int jfr  = r >> 4, lmod = r & 15;
    const int kt   = ck >> 3;
    const int kh   = (ck >> 2) & 1;
    const int lgrp = ck & 3;
    const int lane = lgrp * 16 + lmod;
    char* dst = (char*)W3F + (size_t)p * 524288 + (size_t)kt * 8192
              + (kh * 4 + jfr) * 1024 + lane * 16;
    *(short8*)dst = pk.s;

    if (ck == 0) {
        float b;
        if (n < DH) {
            float s = 0.f;
#pragma unroll
            for (int h = 0; h < NH; ++h) s += bq[n * NH + h];
            b = s;
        } else if (n < 2 * DH) {
            b = bk[n - DH];
        } else {
            b = bv[n - 2 * DH];
        }
        bias[n] = b;
    }
}

// ---------------------------------------------------------------------------
// Kernel 2: qkv_partial[ks][m0..m0+64][0..384] = x[stripe, ks-half] @ W3.
// R10 structure (best so far) + NON-TEMPORAL X loads: X has zero reuse, so
// nt keeps the 268-MB X stream from evicting the 3-MB W3F out of each XCD's
// L2 — B-loads become L2 hits instead of L3 refetches (the theory for the
// ~140-µs plateau). B global->VGPR from fragment-linear W3F (cached, now
// L2-resident). LDS holds only the shared 8-KB A tile.
// A swizzle: 16B chunk c of row r lives at LDS chunk c^(r&7)  (proven R6-R13).
// ---------------------------------------------------------------------------
__global__ __launch_bounds__(384) void gemm_qkv(const float* __restrict__ X,
                         const unsigned short* __restrict__ W3F,
                         float* __restrict__ qkvp, int nsplit) {
    __shared__ __align__(16) unsigned short Asm[BM * BK];        // 8 KB

    // XCD-bijective remap over 256*nsplit blocks (divisible by 8)
    const int nblk  = 256 * nsplit;
    const int chnk  = nblk >> 3;
    const int bid   = blockIdx.x;
    const int wkid  = (bid & 7) * chnk + (bid >> 3);
    const int ks    = wkid >> 8;              // [0, nsplit)
    const int my    = wkid & 255;
    const int m0    = my * BM;
    const int klen  = EMB / nsplit;
    const int koff  = ks * klen;
    const int nt    = klen / BK;

    const int t = threadIdx.x, lane = t & 63, w = t >> 6;   // w in {0..5}
    const int lmod = lane & 15, lgrp = lane >> 4;

    f32x4 acc[4][4] = {};

    // A staging (waves 0-3): wave w covers rows [w*16, w*16+16);
    // instr i covers rows w*16 + i*4 + (lane>>4), 16 B at (lane&15)*16.
    const int arow4 = lane >> 4;
    const float* xp = X + (size_t)(m0 + w * 16 + arow4) * EMB + koff + (lane & 15) * 4;
    const int acs = (lane & 15) >> 1;
    const int ah4 = (lane & 1) * 4;

    // B source: wave w consumes panel w, fragment-linear (cached -> L2)
    const char* bsrc = (const char*)W3F + (size_t)w * 524288
                     + ((size_t)koff >> 6) * 8192 + lane * 16;

    f32x4 av[4];

#define LOAD_AV(T) do { \
    _Pragma("unroll") \
    for (int i = 0; i < 4; ++i) \
        av[i] = __builtin_nontemporal_load((const f32x4*)(xp + (T) * BK + i * 4 * EMB)); \
} while (0)

#define WRITE_A() do { \
    _Pragma("unroll") \
    for (int idx = 0; idx < 4; ++idx) { \
        const int rl = w * 16 + idx * 4 + arow4; \
        union { short4_t s; unsigned int u[2]; } pk; \
        pk.u[0] = cvt2(av[idx].x, av[idx].y); \
        pk.u[1] = cvt2(av[idx].z, av[idx].w); \
        *(short4_t*)(&Asm[rl * BK + ((acs ^ (rl & 7)) << 3) + ah4]) = pk.s; \
    } \
} while (0)

    // prologue: A regs for tile 0
    if (w < 4) LOAD_AV(0);

    for (int tt = 0; tt < nt; ++tt) {
        __syncthreads();                      // readers of previous tile done
        if (w < 4) WRITE_A();                 // av(tile tt); auto vmcnt-wait
        __syncthreads();                      // tile resident
        if (w < 4 && tt + 1 < nt) LOAD_AV(tt + 1);  // streams under compute

        const char* bt = bsrc + (size_t)tt * 8192;
#pragma unroll
        for (int kh = 0; kh < 2; ++kh) {
            short8 af[4], bf[4];
#pragma unroll
            for (int j = 0; j < 4; ++j)
                bf[j] = *(const short8*)(bt + (kh * 4 + j) * 1024);   // L2 hit
            const int cs = ((kh * 4 + lgrp) ^ (lmod & 7)) * 8;
#pragma unroll
            for (int i = 0; i < 4; ++i)
                af[i] = *(const short8*)(&Asm[(i * 16 + lmod) * BK + cs]);
#pragma unroll
            for (int i = 0; i < 4; ++i)
#pragma unroll
                for (int j = 0; j < 4; ++j)
                    acc[i][j] = __builtin_amdgcn_mfma_f32_16x16x32_bf16(af[i], bf[j], acc[i][j], 0, 0, 0);
        }
    }

    // epilogue: C/D layout col = lane&15, row = (lane>>4)*4 + reg
    float* outp = qkvp + (size_t)ks * NTOK * NCOL;
#pragma unroll
    for (int j = 0; j < 4; ++j) {
        const int gcol = w * 64 + j * 16 + lmod;
#pragma unroll
        for (int i = 0; i < 4; ++i) {
            const int grow = m0 + i * 16 + (lgrp << 2);
#pragma unroll
            for (int r = 0; r < 4; ++r)
                outp[(size_t)(grow + r) * NCOL + gcol] = acc[i][j][r];
        }
    }
#undef LOAD_AV
#undef WRITE_A
}

// ---------------------------------------------------------------------------
// Kernel 3: sum split-K partials + bias, per-token rank-1 softmax, broadcast.
// One wave per token, 4 tokens per block. Read-once qkv via nt loads; output
// stream via nt stores (don't evict W3F/L2); hardware exp2.
// ---------------------------------------------------------------------------
__global__ void attn_out(const float* __restrict__ qkv0, const float* __restrict__ qkv1,
                         const float* __restrict__ bias, float* __restrict__ out,
                         int nsplit) {
    __shared__ float kvs[4][DH][2];
    __shared__ float osm[4][DH];
    const int t = threadIdx.x, lane = t & 63, w = t >> 6;
    const int token = blockIdx.x * 4 + w;
    const float* b0 = qkv0 + (size_t)token * NCOL;

    float q0  = __builtin_nontemporal_load(b0 + lane);
    float q1  = __builtin_nontemporal_load(b0 + 64 + lane);
    float kk0 = __builtin_nontemporal_load(b0 + 128 + lane);
    float kk1 = __builtin_nontemporal_load(b0 + 192 + lane);
    float vv0 = __builtin_nontemporal_load(b0 + 256 + lane);
    float vv1 = __builtin_nontemporal_load(b0 + 320 + lane);
    if (nsplit == 2) {
        const float* b1 = qkv1 + (size_t)token * NCOL;
        q0  += __builtin_nontemporal_load(b1 + lane);
        q1  += __builtin_nontemporal_load(b1 + 64 + lane);
        kk0 += __builtin_nontemporal_load(b1 + 128 + lane);
        kk1 += __builtin_nontemporal_load(b1 + 192 + lane);
        vv0 += __builtin_nontemporal_load(b1 + 256 + lane);
        vv1 += __builtin_nontemporal_load(b1 + 320 + lane);
    }
    q0  += bias[lane];       q1  += bias[64 + lane];
    kk0 += bias[128 + lane]; kk1 += bias[192 + lane];
    vv0 += bias[256 + lane]; vv1 += bias[320 + lane];

    kvs[w][lane][0]      = kk0;  kvs[w][lane][1]      = vv0;
    kvs[w][64 + lane][0] = kk1;  kvs[w][64 + lane][1] = vv1;

    float lmax = fmaxf(kk0, kk1), lmin = fminf(kk0, kk1);
#pragma unroll
    for (int off = 32; off; off >>= 1) {
        lmax = fmaxf(lmax, __shfl_xor(lmax, off));
        lmin = fminf(lmin, __shfl_xor(lmin, off));
    }
    __syncthreads();

    const float c  = 0.088388347648318447f * 1.4426950408889634f; // scale * log2(e)
    const float a0 = q0 * c, a1 = q1 * c;
    const float m0 = (a0 >= 0.f) ? a0 * lmax : a0 * lmin;
    const float m1 = (a1 >= 0.f) ? a1 * lmax : a1 * lmin;

    float s00 = 0.f, s01 = 0.f, s10 = 0.f, s11 = 0.f;
#pragma unroll 8
    for (int e = 0; e < DH; ++e) {
        const float2 kv = *(const float2*)&kvs[w][e][0];   // broadcast read
        const float p0 = exp2_hw(fmaf(a0, kv.x, -m0));
        const float p1 = exp2_hw(fmaf(a1, kv.x, -m1));
        s00 += p0;  s01 = fmaf(p0, kv.y, s01);
        s10 += p1;  s11 = fmaf(p1, kv.y, s11);
    }
    osm[w][lane]      = s01 / s00;
    osm[w][64 + lane] = s11 / s10;
    __syncthreads();

    float* orow = out + (size_t)token * (DH * NH);
#pragma unroll
    for (int it = 0; it < 16; ++it) {
        const int idx = it * 64 + lane;          // float4 index within the 4096-row
        const float val = osm[w][idx >> 3];      // d = (idx*4)/32
        f32x4 f4 = {val, val, val, val};
        __builtin_nontemporal_store(f4, (f32x4*)(orow + idx * 4));
    }
}

// ---------------------------------------------------------------------------
extern "C" void kernel_launch(void* const* d_in, const int* in_sizes, int n_in,
                              void* d_out, int out_size, void* d_ws, size_t ws_size,
                              hipStream_t stream) {
    const float* x  = (const float*)d_in[0];
    const float* Wq = (const float*)d_in[1];
    const float* bq = (const float*)d_in[2];
    const float* Wk = (const float*)d_in[3];
    const float* bk = (const float*)d_in[4];
    const float* Wv = (const float*)d_in[5];
    const float* bv = (const float*)d_in[6];
    float* out = (float*)d_out;

    char* ws = (char*)d_ws;
    const size_t off_bias = 3145728;                 // W3F: 6*524288
    const size_t off_q0   = off_bias + 4096;
    const size_t off_q1   = off_q0 + (size_t)NTOK * NCOL * 4;
    const size_t need2    = off_q1 + (size_t)NTOK * NCOL * 4;  // 53,481,472 B

    unsigned short* W3F = (unsigned short*)ws;
    float* bias = (float*)(ws + off_bias);
    float* qkv0 = (float*)(ws + off_q0);
    const int nsplit = (ws_size >= need2) ? 2 : 1;
    float* qkv1 = (nsplit == 2) ? (float*)(ws + off_q1) : qkv0;

    prep_w<<<(NCOL * 512) / 256, 256, 0, stream>>>(Wq, bq, Wk, bk, Wv, bv, W3F, bias);
    gemm_qkv<<<256 * nsplit, 384, 0, stream>>>(x, W3F, qkv0, nsplit);
    attn_out<<<NTOK / 4, 256, 0, stream>>>(qkv0, qkv1, bias, out, nsplit);
}